// Round 2
// baseline (1710.104 us; speedup 1.0000x reference)
//
#include <hip/hip_runtime.h>

#define NA 8192
#define NB 8192
#define N_LAYERS 16
#define ROWS_PER_VC 64                 // rows per v_partial chunk
#define N_VC (NA / ROWS_PER_VC)        // 128 chunks -> grid (4,128)=512 blocks

typedef _Float16 half_t;
typedef _Float16 half4_t __attribute__((ext_vector_type(4)));
typedef _Float16 half8_t __attribute__((ext_vector_type(8)));
typedef float float4_t __attribute__((ext_vector_type(4)));

// ---------------------------------------------------------------------------
// Layer-1 u-update fused with C(fp32) -> E=exp(-C/eps) (fp16) conversion.
// v == 1 implicitly (g starts at 0). Block-per-row, 256 threads.
// Also zeroes s_next[row] for layer-1's v_partial accumulation.
// ---------------------------------------------------------------------------
template <bool WRITE_E>
__global__ __launch_bounds__(256) void sink_u_first(
    const float* __restrict__ C, const float* __restrict__ alpha,
    const float* __restrict__ d_eps, half_t* __restrict__ E,
    float* __restrict__ u, float* __restrict__ s_next)
{
    const int row = blockIdx.x;
    const int t = threadIdx.x;
    const float inv_eps = 1.0f / d_eps[0];
    const float4_t* Crow = (const float4_t*)(C + (size_t)row * NB);
    half4_t* Erow = (half4_t*)(E + (size_t)row * NB);

    float s = 0.0f;
#pragma unroll
    for (int k = 0; k < 8; ++k) {
        const int idx = k * 256 + t;            // float4 group, 2048 per row
        float4_t c = Crow[idx];
        float e0 = __expf(-c.x * inv_eps);
        float e1 = __expf(-c.y * inv_eps);
        float e2 = __expf(-c.z * inv_eps);
        float e3 = __expf(-c.w * inv_eps);
        if (WRITE_E) {
            half4_t h;
            h.x = (_Float16)e0; h.y = (_Float16)e1;
            h.z = (_Float16)e2; h.w = (_Float16)e3;
            Erow[idx] = h;
        }
        s += (e0 + e1) + (e2 + e3);
    }

    __shared__ float sm[256];
    sm[t] = s;
    __syncthreads();
    for (int off = 128; off > 0; off >>= 1) {
        if (t < off) sm[t] += sm[t + off];
        __syncthreads();
    }
    if (t == 0) {
        u[row] = alpha[row] / sm[0];
        s_next[row] = 0.0f;             // prepare colsum buffer for v_partial L0
    }
}

// ---------------------------------------------------------------------------
// u-update, layers 2..16: u[i] = alpha[i] / sum_j E[i,j] * (beta[j]/s_prev[j]).
// One WAVE per row (block = 4 rows), half8 16B loads, shuffle reduction.
// Zeroes s_next[row] for the following v_partial.
// ---------------------------------------------------------------------------
template <bool USE_E>
__global__ __launch_bounds__(256) void sink_u_step(
    const void* __restrict__ mat, const float* __restrict__ s_prev,
    const float* __restrict__ beta, const float* __restrict__ alpha,
    const float* __restrict__ d_eps, float* __restrict__ u,
    float* __restrict__ s_next)
{
    const int wave = threadIdx.x >> 6;
    const int lane = threadIdx.x & 63;
    const int row = blockIdx.x * 4 + wave;

    const float4_t* bb = (const float4_t*)beta;
    const float4_t* ss = (const float4_t*)s_prev;
    float acc = 0.0f;

    if (USE_E) {
        const half8_t* Erow = (const half8_t*)mat + (size_t)row * (NB / 8);
#pragma unroll 4
        for (int k = 0; k < 16; ++k) {
            const int g = k * 64 + lane;        // half8 group, 1024 per row
            half8_t e = Erow[g];
            float4_t b0 = bb[2 * g],     b1 = bb[2 * g + 1];
            float4_t s0 = ss[2 * g],     s1 = ss[2 * g + 1];
            acc += (float)e[0] * (b0.x * __builtin_amdgcn_rcpf(s0.x));
            acc += (float)e[1] * (b0.y * __builtin_amdgcn_rcpf(s0.y));
            acc += (float)e[2] * (b0.z * __builtin_amdgcn_rcpf(s0.z));
            acc += (float)e[3] * (b0.w * __builtin_amdgcn_rcpf(s0.w));
            acc += (float)e[4] * (b1.x * __builtin_amdgcn_rcpf(s1.x));
            acc += (float)e[5] * (b1.y * __builtin_amdgcn_rcpf(s1.y));
            acc += (float)e[6] * (b1.z * __builtin_amdgcn_rcpf(s1.z));
            acc += (float)e[7] * (b1.w * __builtin_amdgcn_rcpf(s1.w));
        }
    } else {
        const float inv_eps = 1.0f / d_eps[0];
        const float4_t* Crow = (const float4_t*)mat + (size_t)row * (NB / 4);
#pragma unroll 4
        for (int k = 0; k < 32; ++k) {
            const int g = k * 64 + lane;        // float4 group, 2048 per row
            float4_t c = Crow[g];
            float4_t b = bb[g], s = ss[g];
            acc += __expf(-c.x * inv_eps) * (b.x * __builtin_amdgcn_rcpf(s.x));
            acc += __expf(-c.y * inv_eps) * (b.y * __builtin_amdgcn_rcpf(s.y));
            acc += __expf(-c.z * inv_eps) * (b.z * __builtin_amdgcn_rcpf(s.z));
            acc += __expf(-c.w * inv_eps) * (b.w * __builtin_amdgcn_rcpf(s.w));
        }
    }

#pragma unroll
    for (int off = 32; off > 0; off >>= 1)
        acc += __shfl_down(acc, off, 64);

    if (lane == 0) {
        u[row] = alpha[row] / acc;
        s_next[row] = 0.0f;             // prepare colsum buffer for next v_partial
    }
}

// ---------------------------------------------------------------------------
// v-update colsums: s_next[j] += sum_{i in 64-row chunk} E[i,j]*u[i], via
// device-scope atomics. Grid (4 col-chunks, 128 row-chunks) x 256 threads;
// thread owns 8 consecutive columns -> fully coalesced 16B/lane fp16 loads.
// ---------------------------------------------------------------------------
template <bool USE_E>
__global__ __launch_bounds__(256) void sink_v_partial(
    const void* __restrict__ mat, const float* __restrict__ u,
    const float* __restrict__ d_eps, float* __restrict__ s_next)
{
    const int cc = blockIdx.x;  // 0..3
    const int rc = blockIdx.y;  // 0..127
    const int t = threadIdx.x;
    const int row0 = rc * ROWS_PER_VC;

    float acc[8];
#pragma unroll
    for (int k = 0; k < 8; ++k) acc[k] = 0.0f;

    if (USE_E) {
        const half8_t* Eb = (const half8_t*)mat;
        const int g = cc * 256 + t;  // half8 group; 1024 per row
#pragma unroll 8
        for (int r = 0; r < ROWS_PER_VC; ++r) {
            const float ur = u[row0 + r];
            half8_t e = Eb[(size_t)(row0 + r) * (NB / 8) + g];
#pragma unroll
            for (int k = 0; k < 8; ++k) acc[k] += ur * (float)e[k];
        }
    } else {
        const float inv_eps = 1.0f / d_eps[0];
        const float4_t* Cb = (const float4_t*)mat;
        const int g = (cc * 256 + t) * 2;  // float4 group; 2048 per row
#pragma unroll 4
        for (int r = 0; r < ROWS_PER_VC; ++r) {
            const float ur = u[row0 + r];
            float4_t c0 = Cb[(size_t)(row0 + r) * (NB / 4) + g];
            float4_t c1 = Cb[(size_t)(row0 + r) * (NB / 4) + g + 1];
            acc[0] += ur * __expf(-c0.x * inv_eps);
            acc[1] += ur * __expf(-c0.y * inv_eps);
            acc[2] += ur * __expf(-c0.z * inv_eps);
            acc[3] += ur * __expf(-c0.w * inv_eps);
            acc[4] += ur * __expf(-c1.x * inv_eps);
            acc[5] += ur * __expf(-c1.y * inv_eps);
            acc[6] += ur * __expf(-c1.z * inv_eps);
            acc[7] += ur * __expf(-c1.w * inv_eps);
        }
    }

    const int col0 = (cc * 256 + t) * 8;
#pragma unroll
    for (int k = 0; k < 8; ++k)
        atomicAdd(&s_next[col0 + k], acc[k]);
}

// ---------------------------------------------------------------------------
// f = eps*log(u), g = eps*log(beta/s_last), concatenated into d_out.
// ---------------------------------------------------------------------------
__global__ __launch_bounds__(256) void sink_finalize(
    const float* __restrict__ u, const float* __restrict__ s_last,
    const float* __restrict__ beta, const float* __restrict__ d_eps,
    float* __restrict__ out)
{
    const int i = blockIdx.x * 256 + threadIdx.x;
    const float eps = d_eps[0];
    if (i < NA) {
        out[i] = eps * logf(u[i]);
    } else if (i < NA + NB) {
        const int j = i - NA;
        out[i] = eps * logf(beta[j] / s_last[j]);
    }
}

extern "C" void kernel_launch(void* const* d_in, const int* in_sizes, int n_in,
                              void* d_out, int out_size, void* d_ws, size_t ws_size,
                              hipStream_t stream)
{
    const float* alpha = (const float*)d_in[0];
    const float* beta  = (const float*)d_in[1];
    const float* C     = (const float*)d_in[2];
    const float* d_eps = (const float*)d_in[3];
    float* out = (float*)d_out;

    const size_t eBytes = (size_t)NA * NB * sizeof(half_t);  // 128 MiB
    const size_t vecBytes = (size_t)NA * sizeof(float);      // 32 KiB

    char* ws = (char*)d_ws;
    const bool useE = ws_size >= eBytes + 3 * vecBytes;

    size_t off = 0;
    half_t* E = nullptr;
    if (useE) { E = (half_t*)ws; off += eBytes; }
    float* u  = (float*)(ws + off); off += vecBytes;
    float* s0 = (float*)(ws + off); off += vecBytes;
    float* s1 = (float*)(ws + off); off += vecBytes;
    float* sbuf[2] = {s0, s1};

    const dim3 blk(256);
    const dim3 gridFirst(NA);           // block per row
    const dim3 gridU(NA / 4);           // wave per row
    const dim3 gridVP(NB / 2048, N_VC); // (4, 128)

    for (int layer = 0; layer < N_LAYERS; ++layer) {
        float* sn = sbuf[layer & 1];
        if (layer == 0) {
            if (useE)
                sink_u_first<true><<<gridFirst, blk, 0, stream>>>(C, alpha, d_eps, E, u, sn);
            else
                sink_u_first<false><<<gridFirst, blk, 0, stream>>>(C, alpha, d_eps, nullptr, u, sn);
        } else {
            float* sp = sbuf[(layer - 1) & 1];
            if (useE)
                sink_u_step<true><<<gridU, blk, 0, stream>>>(E, sp, beta, alpha, d_eps, u, sn);
            else
                sink_u_step<false><<<gridU, blk, 0, stream>>>(C, sp, beta, alpha, d_eps, u, sn);
        }
        if (useE)
            sink_v_partial<true><<<gridVP, blk, 0, stream>>>(E, u, d_eps, sn);
        else
            sink_v_partial<false><<<gridVP, blk, 0, stream>>>(C, u, d_eps, sn);
    }
    sink_finalize<<<dim3((NA + NB) / 256), blk, 0, stream>>>(
        u, sbuf[(N_LAYERS - 1) & 1], beta, d_eps, out);
}

// Round 3
// 1165.946 us; speedup vs baseline: 1.4667x; 1.4667x over previous
//
#include <hip/hip_runtime.h>

#define NA 8192
#define NB 8192
#define N_LAYERS 16
#define ROWS_PER_VC 64                 // rows per v_partial chunk
#define N_VC (NA / ROWS_PER_VC)        // 128 chunks -> grid (4,128)=512 blocks

typedef _Float16 half_t;
typedef _Float16 half8_t __attribute__((ext_vector_type(8)));
typedef float float4_t __attribute__((ext_vector_type(4)));

// ---------------------------------------------------------------------------
// Layer-1 u-update fused with C(fp32) -> E=exp(-C/eps) (fp16) conversion.
// v == 1 implicitly (g starts at 0). Block-per-row, 256 threads, half8 stores.
// ---------------------------------------------------------------------------
template <bool WRITE_E>
__global__ __launch_bounds__(256) void sink_u_first(
    const float* __restrict__ C, const float* __restrict__ alpha,
    const float* __restrict__ d_eps, half_t* __restrict__ E,
    float* __restrict__ u)
{
    const int row = blockIdx.x;
    const int t = threadIdx.x;
    const float inv_eps = 1.0f / d_eps[0];
    const float4_t* Crow = (const float4_t*)(C + (size_t)row * NB);
    half8_t* Erow = (half8_t*)(E + (size_t)row * NB);

    float s = 0.0f;
#pragma unroll
    for (int k = 0; k < 4; ++k) {
        const int g = k * 256 + t;              // half8 group, 1024 per row
        float4_t c0 = Crow[2 * g];
        float4_t c1 = Crow[2 * g + 1];
        float e0 = __expf(-c0.x * inv_eps);
        float e1 = __expf(-c0.y * inv_eps);
        float e2 = __expf(-c0.z * inv_eps);
        float e3 = __expf(-c0.w * inv_eps);
        float e4 = __expf(-c1.x * inv_eps);
        float e5 = __expf(-c1.y * inv_eps);
        float e6 = __expf(-c1.z * inv_eps);
        float e7 = __expf(-c1.w * inv_eps);
        if (WRITE_E) {
            half8_t h;
            h[0] = (_Float16)e0; h[1] = (_Float16)e1;
            h[2] = (_Float16)e2; h[3] = (_Float16)e3;
            h[4] = (_Float16)e4; h[5] = (_Float16)e5;
            h[6] = (_Float16)e6; h[7] = (_Float16)e7;
            Erow[g] = h;
        }
        s += ((e0 + e1) + (e2 + e3)) + ((e4 + e5) + (e6 + e7));
    }

    __shared__ float sm[256];
    sm[t] = s;
    __syncthreads();
    for (int off = 128; off > 0; off >>= 1) {
        if (t < off) sm[t] += sm[t + off];
        __syncthreads();
    }
    if (t == 0) u[row] = alpha[row] / sm[0];
}

// ---------------------------------------------------------------------------
// u-update, layers 2..16: u[i] = alpha[i] / sum_j E[i,j]*v[j].
// Block-per-row, 256 threads, half8 (16B/lane) E loads, precomputed v.
// ---------------------------------------------------------------------------
template <bool USE_E>
__global__ __launch_bounds__(256) void sink_u_step(
    const void* __restrict__ mat, const float* __restrict__ v,
    const float* __restrict__ alpha, const float* __restrict__ d_eps,
    float* __restrict__ u)
{
    const int row = blockIdx.x;
    const int t = threadIdx.x;
    const float4_t* vv = (const float4_t*)v;
    float s = 0.0f;

    if (USE_E) {
        const half8_t* Erow = (const half8_t*)mat + (size_t)row * (NB / 8);
#pragma unroll
        for (int k = 0; k < 4; ++k) {
            const int g = k * 256 + t;          // half8 group, 1024 per row
            half8_t e = Erow[g];
            float4_t w0 = vv[2 * g], w1 = vv[2 * g + 1];
            s += (float)e[0] * w0.x + (float)e[1] * w0.y +
                 (float)e[2] * w0.z + (float)e[3] * w0.w;
            s += (float)e[4] * w1.x + (float)e[5] * w1.y +
                 (float)e[6] * w1.z + (float)e[7] * w1.w;
        }
    } else {
        const float inv_eps = 1.0f / d_eps[0];
        const float4_t* Crow = (const float4_t*)mat + (size_t)row * (NB / 4);
#pragma unroll
        for (int k = 0; k < 8; ++k) {
            const int g = k * 256 + t;
            float4_t c = Crow[g];
            float4_t w = vv[g];
            s += __expf(-c.x * inv_eps) * w.x + __expf(-c.y * inv_eps) * w.y +
                 __expf(-c.z * inv_eps) * w.z + __expf(-c.w * inv_eps) * w.w;
        }
    }

    __shared__ float sm[256];
    sm[t] = s;
    __syncthreads();
    for (int off = 128; off > 0; off >>= 1) {
        if (t < off) sm[t] += sm[t + off];
        __syncthreads();
    }
    if (t == 0) u[row] = alpha[row] / sm[0];
}

// ---------------------------------------------------------------------------
// v-update partial sums: partial[rc][j] = sum_{i in 64-row chunk rc} E[i,j]*u[i].
// Grid (4 col-chunks, 128 row-chunks) x 256 threads; thread owns 8 columns.
// Fully coalesced 16B/lane fp16 loads; deterministic (no atomics).
// ---------------------------------------------------------------------------
template <bool USE_E>
__global__ __launch_bounds__(256) void sink_v_partial(
    const void* __restrict__ mat, const float* __restrict__ u,
    const float* __restrict__ d_eps, float* __restrict__ partial)
{
    const int cc = blockIdx.x;  // 0..3
    const int rc = blockIdx.y;  // 0..127
    const int t = threadIdx.x;
    const int row0 = rc * ROWS_PER_VC;

    float acc[8];
#pragma unroll
    for (int k = 0; k < 8; ++k) acc[k] = 0.0f;

    if (USE_E) {
        const half8_t* Eb = (const half8_t*)mat;
        const int g = cc * 256 + t;  // half8 group; 1024 per row
#pragma unroll 8
        for (int r = 0; r < ROWS_PER_VC; ++r) {
            const float ur = u[row0 + r];
            half8_t e = Eb[(size_t)(row0 + r) * (NB / 8) + g];
#pragma unroll
            for (int k = 0; k < 8; ++k) acc[k] += ur * (float)e[k];
        }
    } else {
        const float inv_eps = 1.0f / d_eps[0];
        const float4_t* Cb = (const float4_t*)mat;
        const int g = (cc * 256 + t) * 2;  // float4 group; 2048 per row
#pragma unroll 4
        for (int r = 0; r < ROWS_PER_VC; ++r) {
            const float ur = u[row0 + r];
            float4_t c0 = Cb[(size_t)(row0 + r) * (NB / 4) + g];
            float4_t c1 = Cb[(size_t)(row0 + r) * (NB / 4) + g + 1];
            acc[0] += ur * __expf(-c0.x * inv_eps);
            acc[1] += ur * __expf(-c0.y * inv_eps);
            acc[2] += ur * __expf(-c0.z * inv_eps);
            acc[3] += ur * __expf(-c0.w * inv_eps);
            acc[4] += ur * __expf(-c1.x * inv_eps);
            acc[5] += ur * __expf(-c1.y * inv_eps);
            acc[6] += ur * __expf(-c1.z * inv_eps);
            acc[7] += ur * __expf(-c1.w * inv_eps);
        }
    }

    float4_t o0 = {acc[0], acc[1], acc[2], acc[3]};
    float4_t o1 = {acc[4], acc[5], acc[6], acc[7]};
    float4_t* p = (float4_t*)(partial + (size_t)rc * NB + (size_t)(cc * 256 + t) * 8);
    p[0] = o0;
    p[1] = o1;
}

// ---------------------------------------------------------------------------
// v-update combine: v[j] = beta[j] / sum_rc partial[rc][j].
// ---------------------------------------------------------------------------
__global__ __launch_bounds__(256) void sink_v_combine(
    const float* __restrict__ partial, const float* __restrict__ beta,
    float* __restrict__ v)
{
    const int col = blockIdx.x * 256 + threadIdx.x;
    float s = 0.0f;
#pragma unroll 8
    for (int rc = 0; rc < N_VC; ++rc) s += partial[(size_t)rc * NB + col];
    v[col] = beta[col] / s;
}

// ---------------------------------------------------------------------------
// f = eps*log(u), g = eps*log(v), concatenated into d_out.
// ---------------------------------------------------------------------------
__global__ __launch_bounds__(256) void sink_finalize(
    const float* __restrict__ u, const float* __restrict__ v,
    const float* __restrict__ d_eps, float* __restrict__ out)
{
    const int i = blockIdx.x * 256 + threadIdx.x;
    const float eps = d_eps[0];
    if (i < NA) {
        out[i] = eps * logf(u[i]);
    } else if (i < NA + NB) {
        out[i] = eps * logf(v[i - NA]);
    }
}

extern "C" void kernel_launch(void* const* d_in, const int* in_sizes, int n_in,
                              void* d_out, int out_size, void* d_ws, size_t ws_size,
                              hipStream_t stream)
{
    const float* alpha = (const float*)d_in[0];
    const float* beta  = (const float*)d_in[1];
    const float* C     = (const float*)d_in[2];
    const float* d_eps = (const float*)d_in[3];
    float* out = (float*)d_out;

    const size_t eBytes = (size_t)NA * NB * sizeof(half_t);   // 128 MiB
    const size_t pBytes = (size_t)N_VC * NB * sizeof(float);  // 4 MiB
    const size_t vecBytes = (size_t)NA * sizeof(float);       // 32 KiB

    char* ws = (char*)d_ws;
    const bool useE = ws_size >= eBytes + pBytes + 2 * vecBytes;

    size_t off = 0;
    half_t* E = nullptr;
    if (useE) { E = (half_t*)ws; off += eBytes; }
    float* partial = (float*)(ws + off); off += pBytes;
    float* u = (float*)(ws + off); off += vecBytes;
    float* v = (float*)(ws + off); off += vecBytes;

    const dim3 blk(256);
    const dim3 gridRow(NA);
    const dim3 gridVP(NB / 2048, N_VC);   // (4, 128)
    const dim3 gridVC(NB / 256);

    for (int layer = 0; layer < N_LAYERS; ++layer) {
        if (layer == 0) {
            if (useE)
                sink_u_first<true><<<gridRow, blk, 0, stream>>>(C, alpha, d_eps, E, u);
            else
                sink_u_first<false><<<gridRow, blk, 0, stream>>>(C, alpha, d_eps, nullptr, u);
        } else {
            if (useE)
                sink_u_step<true><<<gridRow, blk, 0, stream>>>(E, v, alpha, d_eps, u);
            else
                sink_u_step<false><<<gridRow, blk, 0, stream>>>(C, v, alpha, d_eps, u);
        }
        if (useE)
            sink_v_partial<true><<<gridVP, blk, 0, stream>>>(E, u, d_eps, partial);
        else
            sink_v_partial<false><<<gridVP, blk, 0, stream>>>(C, u, d_eps, partial);
        sink_v_combine<<<gridVC, blk, 0, stream>>>(partial, beta, v);
    }
    sink_finalize<<<dim3((NA + NB) / 256), blk, 0, stream>>>(u, v, d_eps, out);
}